// Round 11
// baseline (869.274 us; speedup 1.0000x reference)
//
#include <hip/hip_runtime.h>
#include <hip/hip_bf16.h>
#include <hip/hip_fp16.h>
#include <float.h>

#define D 128
#define NGRAPHS 64
#define BKSHIFT 9
#define BKNODES 512     // nodes per bucket
#define MAXBK 256       // max buckets (N<=131072)
#define PCH 4096        // edges per partition block (256 thr x 16)

typedef _Float16 h8 __attribute__((ext_vector_type(8)));
typedef float f4 __attribute__((ext_vector_type(4)));

// Sliced feature layout: S[slice][node][c], slice=col>>4, c=col&15.
// Per-slice working set = N*32 B = 3.2 MB < 4 MiB per-XCD L2.

// ---- ordered-float encoding for atomicMax on unsigned ----
__device__ __forceinline__ unsigned fkey(float f){
  unsigned u = __float_as_uint(f);
  return (u & 0x80000000u) ? ~u : (u | 0x80000000u);
}
__device__ __forceinline__ float funkey(unsigned k){
  unsigned u = (k & 0x80000000u) ? (k ^ 0x80000000u) : ~k;
  return __uint_as_float(u);
}

// ---- W fp32 row-major -> fp16 MFMA B-frag swizzle for one "pair" unit ----
__device__ __forceinline__ void wcvt_pair(const float* __restrict__ W,
    _Float16* __restrict__ dstp, int pair, int lane){
  int quad = lane >> 4;
  int n    = lane & 15;
  int k0 = pair >> 3;
  int tt = pair & 7;
  _Float16 v[8];
  #pragma unroll
  for (int j = 0; j < 8; j++){
    int k = k0 * 32 + quad * 8 + j;
    v[j] = (_Float16)W[k * 128 + 16 * tt + n];
  }
  *(uint4*)&dstp[((size_t)pair * 64 + lane) * 8] = *(uint4*)v;
}

// 0) W0 swizzle (8 blocks x 4 waves = 32 pairs) + zero bcnt
__global__ __launch_bounds__(256) void k_wcvt0(const float* __restrict__ W0,
    _Float16* __restrict__ Wsw, int* __restrict__ bcnt){
  if (blockIdx.x == 0 && threadIdx.x < MAXBK) bcnt[threadIdx.x] = 0;
  int lane = threadIdx.x & 63;
  int pair = blockIdx.x * 4 + (threadIdx.x >> 6);
  wcvt_pair(W0, Wsw, pair, lane);
}

// sliced-store epilogue from a wave's 16x136 LDS tile
__device__ __forceinline__ void store_sliced(_Float16 (*lds)[136],
    _Float16* __restrict__ CS, size_t sstr, int m0, int lane){
  #pragma unroll
  for (int it = 0; it < 4; it++){
    int u = it * 64 + lane;          // 0..255
    int slice = u & 7;
    int half  = (u >> 3) & 1;
    int row   = u >> 4;
    *(uint4*)&CS[(size_t)slice * sstr + (size_t)(m0 + row) * 16 + half * 8] =
        *(uint4*)&lds[row][slice * 16 + half * 8];
  }
}

// 1) MEGA: [0,gb): gemm0 fp32-A MFMA -> sliced C; [gb,gb+npart): histogram;
//    [gb+npart,+4): W1/W2 swizzle.
__global__ __launch_bounds__(256) void k_mega(
    const float* __restrict__ x, const _Float16* __restrict__ Wsw0,
    _Float16* __restrict__ CS, int M, int gb,
    const int* __restrict__ dst, int* __restrict__ bcnt, int E, int npart,
    const float* __restrict__ W1, const float* __restrict__ W2,
    _Float16* __restrict__ Wsw12){
  __shared__ __align__(16) char smraw[4 * 16 * 136 * 2];  // 17.4 KB union
  int bid = blockIdx.x;
  if (bid < gb){
    _Float16 (*lds)[136] = (_Float16(*)[136])(smraw + (threadIdx.x >> 6) * 16 * 136 * 2);
    int lane = threadIdx.x & 63;
    int quad = lane >> 4;
    int l15  = lane & 15;
    int m0 = bid * 64 + (threadIdx.x >> 6) * 16;
    if (m0 >= M) return;
    f4 acc[8] = {};
    h8 af[4];
    const float* arow = x + (size_t)(m0 + l15) * D;
    #pragma unroll
    for (int k0 = 0; k0 < 4; k0++){
      float4 a = *(const float4*)&arow[k0 * 32 + quad * 8];
      float4 b = *(const float4*)&arow[k0 * 32 + quad * 8 + 4];
      __half2 p0 = __floats2half2_rn(a.x, a.y);
      __half2 p1 = __floats2half2_rn(a.z, a.w);
      __half2 p2 = __floats2half2_rn(b.x, b.y);
      __half2 p3 = __floats2half2_rn(b.z, b.w);
      union { uint4 u; h8 v; } cv;
      cv.u.x = *(unsigned*)&p0; cv.u.y = *(unsigned*)&p1;
      cv.u.z = *(unsigned*)&p2; cv.u.w = *(unsigned*)&p3;
      af[k0] = cv.v;
    }
    #pragma unroll
    for (int k0 = 0; k0 < 4; k0++){
      #pragma unroll
      for (int t = 0; t < 8; t++){
        h8 bf = *(const h8*)&Wsw0[((size_t)(k0 * 8 + t) * 64 + lane) * 8];
        acc[t] = __builtin_amdgcn_mfma_f32_16x16x32_f16(af[k0], bf, acc[t], 0, 0, 0);
      }
    }
    #pragma unroll
    for (int t = 0; t < 8; t++){
      #pragma unroll
      for (int r = 0; r < 4; r++)
        lds[quad * 4 + r][t * 16 + l15] = (_Float16)acc[t][r];
    }
    store_sliced(lds, CS, (size_t)M * 16, m0, lane);
    return;
  }
  bid -= gb;
  if (bid < npart){
    int* h = (int*)smraw;
    int t = threadIdx.x;
    for (int i = t; i < MAXBK; i += 256) h[i] = 0;
    __syncthreads();
    int e0 = bid * PCH;
    #pragma unroll
    for (int j = 0; j < PCH / 256; j++){
      int e = e0 + t + j * 256;
      if (e < E) atomicAdd(&h[dst[e] >> BKSHIFT], 1);
    }
    __syncthreads();
    for (int i = t; i < MAXBK; i += 256) if (h[i]) atomicAdd(&bcnt[i], h[i]);
    return;
  }
  bid -= npart;
  const float* W = (bid < 2) ? W1 : W2;
  _Float16* dstp = Wsw12 + ((bid < 2) ? 0 : 16384);
  int pbase = (bid & 1) * 16;
  int lane = threadIdx.x & 63;
  for (int pp = (threadIdx.x >> 6); pp < 16; pp += 4)
    wcvt_pair(W, dstp, pbase + pp, lane);
}

// 2) scan bucket counts -> bOff[nbk+1], bCur; row_ptr[N]=E; zero pk
__global__ __launch_bounds__(256) void k_bscan(const int* __restrict__ bcnt,
    int* __restrict__ bOff, int* __restrict__ bCur, int* __restrict__ row_ptr,
    unsigned* __restrict__ pk, int nbk, int N, int E){
  __shared__ int sh[256];
  int t = threadIdx.x;
  for (int i = t; i < NGRAPHS * D; i += 256) pk[i] = 0u;
  int v = (t < nbk) ? bcnt[t] : 0;
  sh[t] = v; __syncthreads();
  for (int off = 1; off < 256; off <<= 1){
    int x = (t >= off) ? sh[t - off] : 0;
    __syncthreads();
    sh[t] += x;
    __syncthreads();
  }
  if (t < nbk){ int ex = sh[t] - v; bOff[t] = ex; bCur[t] = ex; }
  if (t == 0){ bOff[nbk] = E; row_ptr[N] = E; }
}

// 3) partition edges into bucket-grouped epart[]
__global__ __launch_bounds__(256) void k_part(const int* __restrict__ src,
    const int* __restrict__ dst, int* __restrict__ bCur,
    uint2* __restrict__ epart, int E){
  __shared__ int scnt[MAXBK], soff[MAXBK], sbase[MAXBK], scur[MAXBK];
  __shared__ int stmp[256];
  __shared__ uint2 stage[PCH];   // 32 KB
  int t = threadIdx.x;
  int e0 = blockIdx.x * PCH;
  int eN = E - e0; if (eN > PCH) eN = PCH;
  for (int i = t; i < MAXBK; i += 256){ scnt[i] = 0; scur[i] = 0; }
  __syncthreads();
  uint2 mye[PCH / 256];
  #pragma unroll
  for (int j = 0; j < PCH / 256; j++){
    int e = e0 + t + j * 256;
    if (e < E){
      mye[j].x = (unsigned)src[e];
      mye[j].y = (unsigned)dst[e];
      atomicAdd(&scnt[mye[j].y >> BKSHIFT], 1);
    }
  }
  __syncthreads();
  int v = scnt[t];
  stmp[t] = v; __syncthreads();
  for (int off = 1; off < 256; off <<= 1){
    int x = (t >= off) ? stmp[t - off] : 0;
    __syncthreads();
    stmp[t] += x;
    __syncthreads();
  }
  soff[t] = stmp[t] - v;
  if (v > 0) sbase[t] = atomicAdd(&bCur[t], v);
  __syncthreads();
  #pragma unroll
  for (int j = 0; j < PCH / 256; j++){
    int e = e0 + t + j * 256;
    if (e < E){
      int b = mye[j].y >> BKSHIFT;
      int l = atomicAdd(&scur[b], 1);
      stage[soff[b] + l] = mye[j];
    }
  }
  __syncthreads();
  for (int j = t; j < eN; j += 256){
    uint2 ed = stage[j];
    int b = (int)(ed.y >> BKSHIFT);
    epart[(size_t)sbase[b] + (j - soff[b])] = ed;
  }
}

// 4) per-bucket CSR build
__global__ __launch_bounds__(256) void k_bfill(const uint2* __restrict__ epart,
    const int* __restrict__ bOff, int* __restrict__ row_ptr,
    int* __restrict__ col, float* __restrict__ dinv, int N){
  __shared__ int hc[BKNODES], off[BKNODES], cur[BKNODES];
  __shared__ int stmp[256];
  int b = blockIdx.x, t = threadIdx.x;
  int base = bOff[b], cntE = bOff[b + 1] - base;
  int node0 = b << BKSHIFT;
  int nloc = N - node0; if (nloc > BKNODES) nloc = BKNODES;
  for (int i = t; i < BKNODES; i += 256) hc[i] = 0;
  __syncthreads();
  for (int j = t; j < cntE; j += 256){
    uint2 ed = epart[(size_t)base + j];
    atomicAdd(&hc[ed.y - node0], 1);
  }
  __syncthreads();
  int a0 = hc[2 * t], a1 = hc[2 * t + 1];
  int s = a0 + a1;
  stmp[t] = s; __syncthreads();
  for (int o = 1; o < 256; o <<= 1){
    int x = (t >= o) ? stmp[t - o] : 0;
    __syncthreads();
    stmp[t] += x;
    __syncthreads();
  }
  int ex = stmp[t] - s;
  off[2 * t] = ex; off[2 * t + 1] = ex + a0;
  __syncthreads();
  for (int i = t; i < nloc; i += 256){
    row_ptr[node0 + i] = base + off[i];
    dinv[node0 + i]    = rsqrtf((float)hc[i] + 1.0f);
    cur[i] = off[i];
  }
  __syncthreads();
  for (int j = t; j < cntE; j += 256){
    uint2 ed = epart[(size_t)base + j];
    int p = atomicAdd(&cur[ed.y - node0], 1);
    col[base + p] = (int)ed.x;
  }
}

// 5) MFMA GEMM, sliced A -> sliced C
__global__ __launch_bounds__(256) void gemm_mfma(const _Float16* __restrict__ AS,
    const _Float16* __restrict__ Wsw, _Float16* __restrict__ CS, int M){
  __shared__ _Float16 lds[4][16][136];
  int wave = threadIdx.x >> 6;
  int lane = threadIdx.x & 63;
  int quad = lane >> 4;
  int l15  = lane & 15;
  int m0 = blockIdx.x * 64 + wave * 16;
  if (m0 >= M) return;
  size_t sstr = (size_t)M * 16;
  f4 acc[8] = {};
  h8 af[4];
  #pragma unroll
  for (int k0 = 0; k0 < 4; k0++){
    int sl = k0 * 2 + (quad >> 1);
    af[k0] = *(const h8*)&AS[(size_t)sl * sstr + (size_t)(m0 + l15) * 16 + (quad & 1) * 8];
  }
  #pragma unroll
  for (int k0 = 0; k0 < 4; k0++){
    #pragma unroll
    for (int t = 0; t < 8; t++){
      h8 bf = *(const h8*)&Wsw[((size_t)(k0 * 8 + t) * 64 + lane) * 8];
      acc[t] = __builtin_amdgcn_mfma_f32_16x16x32_f16(af[k0], bf, acc[t], 0, 0, 0);
    }
  }
  #pragma unroll
  for (int t = 0; t < 8; t++){
    #pragma unroll
    for (int r = 0; r < 4; r++)
      lds[wave][quad * 4 + r][t * 16 + l15] = (_Float16)acc[t][r];
  }
  store_sliced(lds[wave], CS, sstr, m0, lane);
}

// accumulate 4 halves * w into a[4] (fma_mix)
__device__ __forceinline__ void acc4(float* a, uint2 u, float w){
  union { uint2 u; _Float16 h[4]; } cv;
  cv.u = u;
  #pragma unroll
  for (int k = 0; k < 4; k++)
    a[k] += (float)cv.h[k] * w;
}

// 6) sliced CSR aggregation: slice = blockIdx&7 (XCD affinity via round-robin),
//    wave = 8 nodes sequential; lane = way(0..15) x cq(0..3); uint2 gathers.
__global__ __launch_bounds__(256) void k_aggS(const _Float16* __restrict__ tS,
    const int* __restrict__ row_ptr, const int* __restrict__ col,
    const float* __restrict__ dinv, const float* __restrict__ bias,
    _Float16* __restrict__ outS, int relu, int N){
  int slice = blockIdx.x & 7;
  int chunk = blockIdx.x >> 3;
  int wavei = threadIdx.x >> 6;
  int lane  = threadIdx.x & 63;
  int way   = lane >> 2;        // 0..15
  int cq    = (lane & 3) * 4;   // half-offset within 16-col slice
  size_t sstr = (size_t)N * 16;
  const _Float16* ts = tS + (size_t)slice * sstr;
  _Float16* os = outS + (size_t)slice * sstr;
  float4 b4 = *(const float4*)&bias[slice * 16 + cq];
  float bb[4] = {b4.x, b4.y, b4.z, b4.w};
  int node0 = chunk * 32 + wavei * 8;
  int nodeEnd = node0 + 8; if (nodeEnd > N) nodeEnd = N;
  for (int node = node0; node < nodeEnd; node++){
    float di = dinv[node];
    int beg = row_ptr[node], end = row_ptr[node + 1];
    float a[4] = {0.f, 0.f, 0.f, 0.f};
    int j = beg + way;
    for (; j + 16 < end; j += 32){
      int s0 = col[j], s1 = col[j + 16];
      float w0 = dinv[s0] * di;
      float w1 = dinv[s1] * di;
      uint2 u0 = *(const uint2*)&ts[(size_t)s0 * 16 + cq];
      uint2 u1 = *(const uint2*)&ts[(size_t)s1 * 16 + cq];
      acc4(a, u0, w0);
      acc4(a, u1, w1);
    }
    if (j < end){
      int s = col[j];
      float w = dinv[s] * di;
      uint2 u = *(const uint2*)&ts[(size_t)s * 16 + cq];
      acc4(a, u, w);
    }
    #pragma unroll
    for (int k = 0; k < 4; k++){
      a[k] += __shfl_xor(a[k], 4, 64);
      a[k] += __shfl_xor(a[k], 8, 64);
      a[k] += __shfl_xor(a[k], 16, 64);
      a[k] += __shfl_xor(a[k], 32, 64);
    }
    if (way == 0){
      uint2 su = *(const uint2*)&ts[(size_t)node * 16 + cq];
      union { uint2 u; _Float16 h[4]; } sv; sv.u = su;
      float dii = di * di;
      float o[4];
      #pragma unroll
      for (int k = 0; k < 4; k++)
        o[k] = a[k] + (float)sv.h[k] * dii + bb[k];
      if (relu){
        #pragma unroll
        for (int k = 0; k < 4; k++) o[k] = fmaxf(o[k], 0.f);
      }
      __half2 p0 = __floats2half2_rn(o[0], o[1]);
      __half2 p1 = __floats2half2_rn(o[2], o[3]);
      uint2 u;
      u.x = *(unsigned*)&p0;
      u.y = *(unsigned*)&p1;
      *(uint2*)&os[(size_t)node * 16 + cq] = u;
    }
  }
}

// 7) segment-max over sliced input, 64-row chunks, 4-deep load batching.
__global__ __launch_bounds__(128) void k_pool(const _Float16* __restrict__ hS,
    const int* __restrict__ batch, unsigned* __restrict__ pk, int N){
  int d = threadIdx.x;
  int slice = d >> 4, c = d & 15;
  const _Float16* hs = hS + (size_t)slice * N * 16 + c;
  int n0 = blockIdx.x * 64;
  int nEnd = n0 + 64; if (nEnd > N) nEnd = N;
  float cur = -FLT_MAX;
  int curg = batch[n0];
  int n = n0;
  for (; n + 3 < nEnd; n += 4){
    const _Float16* r = &hs[(size_t)n * 16];
    _Float16 v0 = r[0], v1 = r[16], v2 = r[32], v3 = r[48];
    int g0 = batch[n], g1 = batch[n + 1], g2 = batch[n + 2], g3 = batch[n + 3];
    if (g0 != curg){ atomicMax(&pk[curg * D + d], fkey(cur)); cur = -FLT_MAX; curg = g0; }
    cur = fmaxf(cur, (float)v0);
    if (g1 != curg){ atomicMax(&pk[curg * D + d], fkey(cur)); cur = -FLT_MAX; curg = g1; }
    cur = fmaxf(cur, (float)v1);
    if (g2 != curg){ atomicMax(&pk[curg * D + d], fkey(cur)); cur = -FLT_MAX; curg = g2; }
    cur = fmaxf(cur, (float)v2);
    if (g3 != curg){ atomicMax(&pk[curg * D + d], fkey(cur)); cur = -FLT_MAX; curg = g3; }
    cur = fmaxf(cur, (float)v3);
  }
  for (; n < nEnd; n++){
    int g = batch[n];
    if (g != curg){ atomicMax(&pk[curg * D + d], fkey(cur)); cur = -FLT_MAX; curg = g; }
    cur = fmaxf(cur, (float)hs[(size_t)n * 16]);
  }
  atomicMax(&pk[curg * D + d], fkey(cur));
}

// 8) final: out[64,2] = pooled @ Wf + bf   (pk indexed by original col d)
__global__ __launch_bounds__(128) void k_final(const unsigned* __restrict__ pk,
    const float* __restrict__ Wf, const float* __restrict__ bf,
    float* __restrict__ out){
  int t = threadIdx.x;
  int g = t >> 1, c = t & 1;
  float s = bf[c];
  for (int k = 0; k < D; k++)
    s += funkey(pk[g * D + k]) * Wf[k * 2 + c];
  out[g * 2 + c] = s;
}

extern "C" void kernel_launch(void* const* d_in, const int* in_sizes, int n_in,
                              void* d_out, int out_size, void* d_ws, size_t ws_size,
                              hipStream_t stream){
  const float* x   = (const float*)d_in[0];
  const int*   ei  = (const int*)d_in[1];
  const int*   bat = (const int*)d_in[2];
  const float* W0  = (const float*)d_in[3];
  const float* b0  = (const float*)d_in[4];
  const float* W1  = (const float*)d_in[5];
  const float* b1  = (const float*)d_in[6];
  const float* W2  = (const float*)d_in[7];
  const float* b2  = (const float*)d_in[8];
  const float* Wf  = (const float*)d_in[9];
  const float* bf  = (const float*)d_in[10];
  int N = in_sizes[0] / D;
  int E = in_sizes[1] / 2;
  const int* srcp = ei;
  const int* dstp = ei + E;
  int nbk   = (N + BKNODES - 1) / BKNODES;
  int npart = (E + PCH - 1) / PCH;
  int gb    = (N + 63) / 64;

  char* p = (char*)d_ws;
  auto alloc = [&](size_t bytes)->char*{
    char* r = p; p += (bytes + 255) & ~(size_t)255; return r;
  };
  float*     dinv    = (float*)alloc((size_t)N * 4);
  int*       row_ptr = (int*)alloc((size_t)(N + 1) * 4);
  int*       col     = (int*)alloc((size_t)E * 4);
  uint2*     epart   = (uint2*)alloc((size_t)E * 8);
  _Float16*  S1      = (_Float16*)alloc((size_t)N * D * 2);  // sliced
  _Float16*  S2      = (_Float16*)alloc((size_t)N * D * 2);  // sliced
  _Float16*  Wsw     = (_Float16*)alloc((size_t)3 * 16384 * 2);
  unsigned*  pk      = (unsigned*)alloc((size_t)NGRAPHS * D * 4);
  int*       bcnt    = (int*)alloc((size_t)MAXBK * 4);
  int*       bOff    = (int*)alloc((size_t)(MAXBK + 1) * 4);
  int*       bCur    = (int*)alloc((size_t)MAXBK * 4);

  // W0 swizzle + bcnt zero
  k_wcvt0<<<8, 256, 0, stream>>>(W0, Wsw, bcnt);
  // gemm0 (x -> S1 sliced) || bucket histogram || W1/W2 swizzle
  k_mega<<<gb + npart + 4, 256, 0, stream>>>(x, Wsw, S1, N, gb,
      dstp, bcnt, E, npart, W1, W2, Wsw + 16384);
  k_bscan<<<1, 256, 0, stream>>>(bcnt, bOff, bCur, row_ptr, pk, nbk, N, E);
  k_part<<<npart, 256, 0, stream>>>(srcp, dstp, bCur, epart, E);
  k_bfill<<<nbk, 256, 0, stream>>>(epart, bOff, row_ptr, col, dinv, N);

  int ablocks = ((N + 31) / 32) * 8;
  // layer 0: agg(S1 -> S2, relu)
  k_aggS<<<ablocks, 256, 0, stream>>>(S1, row_ptr, col, dinv, b0, S2, 1, N);
  // layer 1: gemm(S2 -> S1), agg(S1 -> S2, relu)
  gemm_mfma<<<gb, 256, 0, stream>>>(S2, Wsw + 16384, S1, N);
  k_aggS<<<ablocks, 256, 0, stream>>>(S1, row_ptr, col, dinv, b1, S2, 1, N);
  // layer 2: gemm(S2 -> S1), agg(S1 -> S2, no relu)
  gemm_mfma<<<gb, 256, 0, stream>>>(S2, Wsw + 32768, S1, N);
  k_aggS<<<ablocks, 256, 0, stream>>>(S1, row_ptr, col, dinv, b2, S2, 0, N);
  // pool + classifier
  k_pool<<<(N + 63) / 64, 128, 0, stream>>>(S2, bat, pk, N);
  k_final<<<1, 128, 0, stream>>>(pk, Wf, bf, (float*)d_out);
}

// Round 12
// 408.789 us; speedup vs baseline: 2.1265x; 2.1265x over previous
//
#include <hip/hip_runtime.h>
#include <hip/hip_bf16.h>
#include <hip/hip_fp16.h>
#include <float.h>

#define D 128
#define NGRAPHS 64
#define BKSHIFT 9
#define BKNODES 512     // nodes per bucket
#define MAXBK 256       // max buckets (N<=131072)
#define PCH 2048        // edges per partition block (256 thr x 8)

typedef _Float16 h8 __attribute__((ext_vector_type(8)));
typedef float f4 __attribute__((ext_vector_type(4)));

// ---- ordered-float encoding for atomicMax on unsigned ----
__device__ __forceinline__ unsigned fkey(float f){
  unsigned u = __float_as_uint(f);
  return (u & 0x80000000u) ? ~u : (u | 0x80000000u);
}
__device__ __forceinline__ float funkey(unsigned k){
  unsigned u = (k & 0x80000000u) ? (k ^ 0x80000000u) : ~k;
  return __uint_as_float(u);
}

// ---- W fp32 row-major -> fp16 MFMA B-frag swizzle for one "pair" unit ----
__device__ __forceinline__ void wcvt_pair(const float* __restrict__ W,
    _Float16* __restrict__ dstp, int pair, int lane){
  int quad = lane >> 4;
  int n    = lane & 15;
  int k0 = pair >> 3;
  int tt = pair & 7;
  _Float16 v[8];
  #pragma unroll
  for (int j = 0; j < 8; j++){
    int k = k0 * 32 + quad * 8 + j;
    v[j] = (_Float16)W[k * 128 + 16 * tt + n];
  }
  *(uint4*)&dstp[((size_t)pair * 64 + lane) * 8] = *(uint4*)v;
}

// 0) W0 swizzle (8 blocks x 4 waves = 32 pairs) + zero bcnt
__global__ __launch_bounds__(256) void k_wcvt0(const float* __restrict__ W0,
    _Float16* __restrict__ Wsw, int* __restrict__ bcnt){
  if (blockIdx.x == 0 && threadIdx.x < MAXBK) bcnt[threadIdx.x] = 0;
  int lane = threadIdx.x & 63;
  int pair = blockIdx.x * 4 + (threadIdx.x >> 6);
  wcvt_pair(W0, Wsw, pair, lane);
}

// 1) MEGA: [0,gb): gemm0 fp32-A MFMA (row-major out); [gb,gb+nh): histogram;
//    [gb+nh,+4): W1/W2 swizzle.
#define HCH 4096   // histogram chunk
__global__ __launch_bounds__(256) void k_mega(
    const float* __restrict__ x, const _Float16* __restrict__ Wsw0,
    _Float16* __restrict__ C, int M, int gb,
    const int* __restrict__ dst, int* __restrict__ bcnt, int E, int nh,
    const float* __restrict__ W1, const float* __restrict__ W2,
    _Float16* __restrict__ Wsw12){
  __shared__ __align__(16) char smraw[4 * 16 * 136 * 2];  // 17.4 KB union
  int bid = blockIdx.x;
  if (bid < gb){
    _Float16 (*lds)[136] = (_Float16(*)[136])(smraw + (threadIdx.x >> 6) * 16 * 136 * 2);
    int lane = threadIdx.x & 63;
    int quad = lane >> 4;
    int l15  = lane & 15;
    int m0 = bid * 64 + (threadIdx.x >> 6) * 16;
    if (m0 >= M) return;
    f4 acc[8] = {};
    h8 af[4];
    const float* arow = x + (size_t)(m0 + l15) * D;
    #pragma unroll
    for (int k0 = 0; k0 < 4; k0++){
      float4 a = *(const float4*)&arow[k0 * 32 + quad * 8];
      float4 b = *(const float4*)&arow[k0 * 32 + quad * 8 + 4];
      __half2 p0 = __floats2half2_rn(a.x, a.y);
      __half2 p1 = __floats2half2_rn(a.z, a.w);
      __half2 p2 = __floats2half2_rn(b.x, b.y);
      __half2 p3 = __floats2half2_rn(b.z, b.w);
      union { uint4 u; h8 v; } cv;
      cv.u.x = *(unsigned*)&p0; cv.u.y = *(unsigned*)&p1;
      cv.u.z = *(unsigned*)&p2; cv.u.w = *(unsigned*)&p3;
      af[k0] = cv.v;
    }
    #pragma unroll
    for (int k0 = 0; k0 < 4; k0++){
      #pragma unroll
      for (int t = 0; t < 8; t++){
        h8 bf = *(const h8*)&Wsw0[((size_t)(k0 * 8 + t) * 64 + lane) * 8];
        acc[t] = __builtin_amdgcn_mfma_f32_16x16x32_f16(af[k0], bf, acc[t], 0, 0, 0);
      }
    }
    #pragma unroll
    for (int t = 0; t < 8; t++){
      #pragma unroll
      for (int r = 0; r < 4; r++)
        lds[quad * 4 + r][t * 16 + l15] = (_Float16)acc[t][r];
    }
    #pragma unroll
    for (int it = 0; it < 4; it++){
      int idx = it * 64 + lane;
      int row = idx >> 4;
      int ch  = idx & 15;
      *(uint4*)&C[(size_t)(m0 + row) * D + ch * 8] = *(uint4*)&lds[row][ch * 8];
    }
    return;
  }
  bid -= gb;
  if (bid < nh){
    int* h = (int*)smraw;
    int t = threadIdx.x;
    for (int i = t; i < MAXBK; i += 256) h[i] = 0;
    __syncthreads();
    int e0 = bid * HCH;
    #pragma unroll
    for (int j = 0; j < HCH / 256; j++){
      int e = e0 + t + j * 256;
      if (e < E) atomicAdd(&h[dst[e] >> BKSHIFT], 1);
    }
    __syncthreads();
    for (int i = t; i < MAXBK; i += 256) if (h[i]) atomicAdd(&bcnt[i], h[i]);
    return;
  }
  bid -= nh;
  const float* W = (bid < 2) ? W1 : W2;
  _Float16* dstp = Wsw12 + ((bid < 2) ? 0 : 16384);
  int pbase = (bid & 1) * 16;
  int lane = threadIdx.x & 63;
  for (int pp = (threadIdx.x >> 6); pp < 16; pp += 4)
    wcvt_pair(W, dstp, pbase + pp, lane);
}

// 2) scan bucket counts -> bOff[nbk+1], bCur; row_ptr[N]=E; zero pk
__global__ __launch_bounds__(256) void k_bscan(const int* __restrict__ bcnt,
    int* __restrict__ bOff, int* __restrict__ bCur, int* __restrict__ row_ptr,
    unsigned* __restrict__ pk, int nbk, int N, int E){
  __shared__ int sh[256];
  int t = threadIdx.x;
  for (int i = t; i < NGRAPHS * D; i += 256) pk[i] = 0u;
  int v = (t < nbk) ? bcnt[t] : 0;
  sh[t] = v; __syncthreads();
  for (int off = 1; off < 256; off <<= 1){
    int x = (t >= off) ? sh[t - off] : 0;
    __syncthreads();
    sh[t] += x;
    __syncthreads();
  }
  if (t < nbk){ int ex = sh[t] - v; bOff[t] = ex; bCur[t] = ex; }
  if (t == 0){ bOff[nbk] = E; row_ptr[N] = E; }
}

// 3) partition edges into bucket-grouped epart[] (PCH=2048 -> 16KB stage)
__global__ __launch_bounds__(256) void k_part(const int* __restrict__ src,
    const int* __restrict__ dst, int* __restrict__ bCur,
    uint2* __restrict__ epart, int E){
  __shared__ int scnt[MAXBK], soff[MAXBK], sbase[MAXBK], scur[MAXBK];
  __shared__ int stmp[256];
  __shared__ uint2 stage[PCH];   // 16 KB
  int t = threadIdx.x;
  int e0 = blockIdx.x * PCH;
  int eN = E - e0; if (eN > PCH) eN = PCH;
  for (int i = t; i < MAXBK; i += 256){ scnt[i] = 0; scur[i] = 0; }
  __syncthreads();
  uint2 mye[PCH / 256];
  #pragma unroll
  for (int j = 0; j < PCH / 256; j++){
    int e = e0 + t + j * 256;
    if (e < E){
      mye[j].x = (unsigned)src[e];
      mye[j].y = (unsigned)dst[e];
      atomicAdd(&scnt[mye[j].y >> BKSHIFT], 1);
    }
  }
  __syncthreads();
  int v = scnt[t];
  stmp[t] = v; __syncthreads();
  for (int off = 1; off < 256; off <<= 1){
    int x = (t >= off) ? stmp[t - off] : 0;
    __syncthreads();
    stmp[t] += x;
    __syncthreads();
  }
  soff[t] = stmp[t] - v;
  if (v > 0) sbase[t] = atomicAdd(&bCur[t], v);
  __syncthreads();
  #pragma unroll
  for (int j = 0; j < PCH / 256; j++){
    int e = e0 + t + j * 256;
    if (e < E){
      int b = mye[j].y >> BKSHIFT;
      int l = atomicAdd(&scur[b], 1);
      stage[soff[b] + l] = mye[j];
    }
  }
  __syncthreads();
  for (int j = t; j < eN; j += 256){
    uint2 ed = stage[j];
    int b = (int)(ed.y >> BKSHIFT);
    epart[(size_t)sbase[b] + (j - soff[b])] = ed;
  }
}

// 4) per-bucket CSR build: row_ptr, col, dinv — all state in LDS, confined writes
__global__ __launch_bounds__(256) void k_bfill(const uint2* __restrict__ epart,
    const int* __restrict__ bOff, int* __restrict__ row_ptr,
    int* __restrict__ col, float* __restrict__ dinv, int N){
  __shared__ int hc[BKNODES], off[BKNODES], cur[BKNODES];
  __shared__ int stmp[256];
  int b = blockIdx.x, t = threadIdx.x;
  int base = bOff[b], cntE = bOff[b + 1] - base;
  int node0 = b << BKSHIFT;
  int nloc = N - node0; if (nloc > BKNODES) nloc = BKNODES;
  for (int i = t; i < BKNODES; i += 256) hc[i] = 0;
  __syncthreads();
  for (int j = t; j < cntE; j += 256){
    uint2 ed = epart[(size_t)base + j];
    atomicAdd(&hc[ed.y - node0], 1);
  }
  __syncthreads();
  int a0 = hc[2 * t], a1 = hc[2 * t + 1];
  int s = a0 + a1;
  stmp[t] = s; __syncthreads();
  for (int o = 1; o < 256; o <<= 1){
    int x = (t >= o) ? stmp[t - o] : 0;
    __syncthreads();
    stmp[t] += x;
    __syncthreads();
  }
  int ex = stmp[t] - s;
  off[2 * t] = ex; off[2 * t + 1] = ex + a0;
  __syncthreads();
  for (int i = t; i < nloc; i += 256){
    row_ptr[node0 + i] = base + off[i];
    dinv[node0 + i]    = rsqrtf((float)hc[i] + 1.0f);
    cur[i] = off[i];
  }
  __syncthreads();
  for (int j = t; j < cntE; j += 256){
    uint2 ed = epart[(size_t)base + j];
    int p = atomicAdd(&cur[ed.y - node0], 1);
    col[base + p] = (int)ed.x;
  }
}

// 5) MFMA GEMM, fp16 A (row-major) -> fp16 C (row-major)
__global__ __launch_bounds__(256) void gemm_mfma(const _Float16* __restrict__ A,
    const _Float16* __restrict__ Wsw, _Float16* __restrict__ C, int M){
  __shared__ _Float16 lds[4][16][136];
  int wave = threadIdx.x >> 6;
  int lane = threadIdx.x & 63;
  int quad = lane >> 4;
  int l15  = lane & 15;
  int m0 = blockIdx.x * 64 + wave * 16;
  if (m0 >= M) return;
  f4 acc[8] = {};
  h8 af[4];
  const _Float16* arow = A + (size_t)(m0 + l15) * D;
  #pragma unroll
  for (int k0 = 0; k0 < 4; k0++)
    af[k0] = *(const h8*)&arow[k0 * 32 + quad * 8];
  #pragma unroll
  for (int k0 = 0; k0 < 4; k0++){
    #pragma unroll
    for (int t = 0; t < 8; t++){
      h8 bf = *(const h8*)&Wsw[((size_t)(k0 * 8 + t) * 64 + lane) * 8];
      acc[t] = __builtin_amdgcn_mfma_f32_16x16x32_f16(af[k0], bf, acc[t], 0, 0, 0);
    }
  }
  #pragma unroll
  for (int t = 0; t < 8; t++){
    #pragma unroll
    for (int r = 0; r < 4; r++)
      lds[wave][quad * 4 + r][t * 16 + l15] = (_Float16)acc[t][r];
  }
  #pragma unroll
  for (int it = 0; it < 4; it++){
    int idx = it * 64 + lane;
    int row = idx >> 4;
    int ch  = idx & 15;
    *(uint4*)&C[(size_t)(m0 + row) * D + ch * 8] = *(uint4*)&lds[wave][row][ch * 8];
  }
}

// accumulate 8 halves * w into acc[8]; (float)h * w + acc -> v_fma_mix_f32
__device__ __forceinline__ void accm(float* acc, uint4 u, float w){
  union { uint4 u; _Float16 h[8]; } cv;
  cv.u = u;
  #pragma unroll
  for (int k = 0; k < 8; k++)
    acc[k] += (float)cv.h[k] * w;
}

// 6) CSR aggregation: one wave per node, 4 gather chains/lane, fp16 in/out.
__global__ __launch_bounds__(256) void k_agg(const __half* __restrict__ t,
    const int* __restrict__ row_ptr, const int* __restrict__ col,
    const float* __restrict__ dinv, const float* __restrict__ bias,
    __half* __restrict__ outh, int relu, int N){
  int node = blockIdx.x * 4 + (threadIdx.x >> 6);
  if (node >= N) return;
  int lane = threadIdx.x & 63;
  int way  = lane >> 4;          // 0..3
  int cg   = (lane & 15) * 8;    // first col of this lane's 8-half group
  float di = dinv[node];
  int beg = row_ptr[node], end = row_ptr[node + 1];
  float acc[8] = {0.f,0.f,0.f,0.f,0.f,0.f,0.f,0.f};
  int j = beg + way;
  for (; j + 12 < end; j += 16){
    int s0 = col[j], s1 = col[j + 4], s2 = col[j + 8], s3 = col[j + 12];
    float w0 = dinv[s0] * di;
    float w1 = dinv[s1] * di;
    float w2 = dinv[s2] * di;
    float w3 = dinv[s3] * di;
    uint4 u0 = *(const uint4*)&t[(size_t)s0 * D + cg];
    uint4 u1 = *(const uint4*)&t[(size_t)s1 * D + cg];
    uint4 u2 = *(const uint4*)&t[(size_t)s2 * D + cg];
    uint4 u3 = *(const uint4*)&t[(size_t)s3 * D + cg];
    accm(acc, u0, w0);
    accm(acc, u1, w1);
    accm(acc, u2, w2);
    accm(acc, u3, w3);
  }
  for (; j < end; j += 4){
    int s = col[j];
    float w = dinv[s] * di;
    uint4 u = *(const uint4*)&t[(size_t)s * D + cg];
    accm(acc, u, w);
  }
  #pragma unroll
  for (int k = 0; k < 8; k++){
    acc[k] += __shfl_xor(acc[k], 16, 64);
    acc[k] += __shfl_xor(acc[k], 32, 64);
  }
  if (way == 0){
    uint4 su = *(const uint4*)&t[(size_t)node * D + cg];
    union { uint4 u; _Float16 h[8]; } sv; sv.u = su;
    float dii = di * di;
    float4 b0 = *(const float4*)&bias[cg];
    float4 b1 = *(const float4*)&bias[cg + 4];
    float bb[8] = {b0.x, b0.y, b0.z, b0.w, b1.x, b1.y, b1.z, b1.w};
    float o[8];
    #pragma unroll
    for (int k = 0; k < 8; k++)
      o[k] = acc[k] + (float)sv.h[k] * dii + bb[k];
    if (relu){
      #pragma unroll
      for (int k = 0; k < 8; k++) o[k] = fmaxf(o[k], 0.f);
    }
    __half2 p0 = __floats2half2_rn(o[0], o[1]);
    __half2 p1 = __floats2half2_rn(o[2], o[3]);
    __half2 p2 = __floats2half2_rn(o[4], o[5]);
    __half2 p3 = __floats2half2_rn(o[6], o[7]);
    uint4 u;
    u.x = *(unsigned*)&p0; u.y = *(unsigned*)&p1;
    u.z = *(unsigned*)&p2; u.w = *(unsigned*)&p3;
    *(uint4*)&outh[(size_t)node * D + cg] = u;
  }
}

// 7) chunked segment-max (fp16 input), 64-row chunks, 4-deep load batching.
__global__ __launch_bounds__(128) void k_pool(const __half* __restrict__ h,
    const int* __restrict__ batch, unsigned* __restrict__ pk, int N){
  int d = threadIdx.x;
  int n0 = blockIdx.x * 64;
  int nEnd = n0 + 64; if (nEnd > N) nEnd = N;
  float cur = -FLT_MAX;
  int curg = batch[n0];
  int n = n0;
  for (; n + 3 < nEnd; n += 4){
    const __half* r = &h[(size_t)n * D + d];
    __half v0 = r[0], v1 = r[D], v2 = r[2 * D], v3 = r[3 * D];
    int g0 = batch[n], g1 = batch[n + 1], g2 = batch[n + 2], g3 = batch[n + 3];
    if (g0 != curg){ atomicMax(&pk[curg * D + d], fkey(cur)); cur = -FLT_MAX; curg = g0; }
    cur = fmaxf(cur, __half2float(v0));
    if (g1 != curg){ atomicMax(&pk[curg * D + d], fkey(cur)); cur = -FLT_MAX; curg = g1; }
    cur = fmaxf(cur, __half2float(v1));
    if (g2 != curg){ atomicMax(&pk[curg * D + d], fkey(cur)); cur = -FLT_MAX; curg = g2; }
    cur = fmaxf(cur, __half2float(v2));
    if (g3 != curg){ atomicMax(&pk[curg * D + d], fkey(cur)); cur = -FLT_MAX; curg = g3; }
    cur = fmaxf(cur, __half2float(v3));
  }
  for (; n < nEnd; n++){
    int g = batch[n];
    if (g != curg){ atomicMax(&pk[curg * D + d], fkey(cur)); cur = -FLT_MAX; curg = g; }
    cur = fmaxf(cur, __half2float(h[(size_t)n * D + d]));
  }
  atomicMax(&pk[curg * D + d], fkey(cur));
}

// 8) final: out[64,2] = pooled @ Wf + bf
__global__ __launch_bounds__(128) void k_final(const unsigned* __restrict__ pk,
    const float* __restrict__ Wf, const float* __restrict__ bf,
    float* __restrict__ out){
  int t = threadIdx.x;
  int g = t >> 1, c = t & 1;
  float s = bf[c];
  for (int k = 0; k < D; k++)
    s += funkey(pk[g * D + k]) * Wf[k * 2 + c];
  out[g * 2 + c] = s;
}

extern "C" void kernel_launch(void* const* d_in, const int* in_sizes, int n_in,
                              void* d_out, int out_size, void* d_ws, size_t ws_size,
                              hipStream_t stream){
  const float* x   = (const float*)d_in[0];
  const int*   ei  = (const int*)d_in[1];
  const int*   bat = (const int*)d_in[2];
  const float* W0  = (const float*)d_in[3];
  const float* b0  = (const float*)d_in[4];
  const float* W1  = (const float*)d_in[5];
  const float* b1  = (const float*)d_in[6];
  const float* W2  = (const float*)d_in[7];
  const float* b2  = (const float*)d_in[8];
  const float* Wf  = (const float*)d_in[9];
  const float* bf  = (const float*)d_in[10];
  int N = in_sizes[0] / D;
  int E = in_sizes[1] / 2;
  const int* srcp = ei;
  const int* dstp = ei + E;
  int nbk   = (N + BKNODES - 1) / BKNODES;
  int npart = (E + PCH - 1) / PCH;
  int nh    = (E + HCH - 1) / HCH;
  int gb    = (N + 63) / 64;

  char* p = (char*)d_ws;
  auto alloc = [&](size_t bytes)->char*{
    char* r = p; p += (bytes + 255) & ~(size_t)255; return r;
  };
  float*     dinv    = (float*)alloc((size_t)N * 4);
  int*       row_ptr = (int*)alloc((size_t)(N + 1) * 4);
  int*       col     = (int*)alloc((size_t)E * 4);
  uint2*     epart   = (uint2*)alloc((size_t)E * 8);
  _Float16*  tmp     = (_Float16*)alloc((size_t)N * D * 2);
  _Float16*  tmp2    = (_Float16*)alloc((size_t)N * D * 2);
  _Float16*  Wsw     = (_Float16*)alloc((size_t)3 * 16384 * 2);
  unsigned*  pk      = (unsigned*)alloc((size_t)NGRAPHS * D * 4);
  int*       bcnt    = (int*)alloc((size_t)MAXBK * 4);
  int*       bOff    = (int*)alloc((size_t)(MAXBK + 1) * 4);
  int*       bCur    = (int*)alloc((size_t)MAXBK * 4);

  // W0 swizzle + bcnt zero
  k_wcvt0<<<8, 256, 0, stream>>>(W0, Wsw, bcnt);
  // gemm0 (x -> tmp) || bucket histogram || W1/W2 swizzle
  k_mega<<<gb + nh + 4, 256, 0, stream>>>(x, Wsw, tmp, N, gb,
      dstp, bcnt, E, nh, W1, W2, Wsw + 16384);
  k_bscan<<<1, 256, 0, stream>>>(bcnt, bOff, bCur, row_ptr, pk, nbk, N, E);
  k_part<<<npart, 256, 0, stream>>>(srcp, dstp, bCur, epart, E);
  k_bfill<<<nbk, 256, 0, stream>>>(epart, bOff, row_ptr, col, dinv, N);

  int ablocks = (N + 3) / 4;
  // layer 0: agg(tmp -> tmp2, relu)
  k_agg<<<ablocks, 256, 0, stream>>>((const __half*)tmp, row_ptr, col, dinv, b0, (__half*)tmp2, 1, N);
  // layer 1: gemm(tmp2 -> tmp), agg(tmp -> tmp2, relu)
  gemm_mfma<<<gb, 256, 0, stream>>>(tmp2, Wsw + 16384, tmp, N);
  k_agg<<<ablocks, 256, 0, stream>>>((const __half*)tmp, row_ptr, col, dinv, b1, (__half*)tmp2, 1, N);
  // layer 2: gemm(tmp2 -> tmp), agg(tmp -> tmp2, no relu)
  gemm_mfma<<<gb, 256, 0, stream>>>(tmp2, Wsw + 32768, tmp, N);
  k_agg<<<ablocks, 256, 0, stream>>>((const __half*)tmp, row_ptr, col, dinv, b2, (__half*)tmp2, 0, N);
  // pool + classifier
  k_pool<<<(N + 63) / 64, 128, 0, stream>>>((const __half*)tmp2, bat, pk, N);
  k_final<<<1, 128, 0, stream>>>(pk, Wf, bf, (float*)d_out);
}